// Round 8
// baseline (149.104 us; speedup 1.0000x reference)
//
#include <hip/hip_runtime.h>

// ---------------------------------------------------------------------------
// GPT-2 style MHA block: qkv = x@W_attn+b; causal softmax(QK^T)V; out@W_proj+b
// B=1, S=4096, D=768, H=12, HD=64.  All heavy math in bf16 MFMA (fp32 accum).
// Attention: split-K flash decoding, persistent-block work queue (atomic
// ticket), single-buffered K/V LDS (24KB), RAW barriers (lgkmcnt-only; no
// vmcnt(0) drain -> prefetch loads float across barriers), cvt_pk P-stores.
// ---------------------------------------------------------------------------

typedef short bf16x8 __attribute__((ext_vector_type(8)));      // MFMA A/B frag
typedef float f32x4 __attribute__((ext_vector_type(4)));       // MFMA C/D frag
typedef unsigned short u16x8_t __attribute__((ext_vector_type(8)));
typedef unsigned short u16x4_t __attribute__((ext_vector_type(4)));

#define ATT_S  4096
#define ATT_D  768
#define ATT_3D 2304
#define ATT_H  12
#define LOG2E  1.44269504089f
#define NUM_UNITS 1920

__device__ __forceinline__ unsigned short f2b(float f) {
  union { float f; unsigned int u; } v; v.f = f;
  unsigned int r = v.u + 0x7fffu + ((v.u >> 16) & 1u);   // RNE
  return (unsigned short)(r >> 16);
}
__device__ __forceinline__ float b2f(unsigned short b) {
  union { unsigned int u; float f; } v; v.u = ((unsigned int)b) << 16;
  return v.f;
}
// packed f32x2 -> bf16x2 (RNE), single HW instruction (guide T12 recipe)
__device__ __forceinline__ unsigned int cvtpk(float a, float b) {
  unsigned int r;
  asm("v_cvt_pk_bf16_f32 %0, %1, %2" : "=v"(r) : "v"(a), "v"(b));
  return r;
}

__device__ __forceinline__ f32x4 mfma16(bf16x8 a, bf16x8 b, f32x4 c) {
  return __builtin_amdgcn_mfma_f32_16x16x32_bf16(a, b, c, 0, 0, 0);
}

__device__ __forceinline__ void glds16(const void* g, void* l) {
  __builtin_amdgcn_global_load_lds((__attribute__((address_space(1))) void*)g,
                                   (__attribute__((address_space(3))) void*)l,
                                   16, 0, 0);
}

// raw barrier: LDS ops complete, but NO vmcnt drain (prefetch stays in
// flight; compiler inserts counted vmcnt before kr/vr first use).
__device__ __forceinline__ void lbar() {
  asm volatile("s_waitcnt lgkmcnt(0)" ::: "memory");
  __builtin_amdgcn_s_barrier();
}

// element offset of the 16B chunk c in row `row` of a pitch-64 bf16 LDS tile,
// with XOR slot swizzle (T2): spreads row-varying b128 reads across banks.
__device__ __forceinline__ int swz8(int row, int c) {
  return row * 64 + ((c ^ (row & 7)) << 3);
}

// --------------------------- pre-pass kernels ------------------------------

__global__ __launch_bounds__(256) void convert_f32_bf16(
    const float* __restrict__ in, unsigned short* __restrict__ out, int n4) {
  int i = blockIdx.x * 256 + threadIdx.x;
  if (i >= n4) return;
  float4 v = ((const float4*)in)[i];
  u16x4_t o;
  o[0] = f2b(v.x); o[1] = f2b(v.y); o[2] = f2b(v.z); o[3] = f2b(v.w);
  ((u16x4_t*)out)[i] = o;
}

// W[K][N] f32  ->  WT[N][K] bf16   (both sides coalesced via 32x33 LDS tile)
__global__ __launch_bounds__(256) void transpose_conv(
    const float* __restrict__ W, unsigned short* __restrict__ WT, int K, int N) {
  __shared__ float tile[32][33];
  int bx = blockIdx.x, by = blockIdx.y;
  int tx = threadIdx.x & 31, ty = threadIdx.x >> 5;
#pragma unroll
  for (int k = 0; k < 4; k++)
    tile[ty + k * 8][tx] = W[(size_t)(by * 32 + ty + k * 8) * N + bx * 32 + tx];
  __syncthreads();
#pragma unroll
  for (int k = 0; k < 4; k++)
    WT[(size_t)(bx * 32 + ty + k * 8) * K + by * 32 + tx] = f2b(tile[tx][ty + k * 8]);
}

// --------------------------- bf16 MFMA GEMM --------------------------------

template <int BF16_OUT>
__global__ __launch_bounds__(256) void gemm_bias(
    const unsigned short* __restrict__ A, const unsigned short* __restrict__ Bt,
    const float* __restrict__ bias, void* __restrict__ Cout,
    int M, int N, int K) {
  __shared__ unsigned short As[128 * 32];
  __shared__ unsigned short Bs[128 * 32];
  const int t = threadIdx.x;
  const int lane = t & 63;
  const int wave = t >> 6;
  const int wr = wave >> 1, wc = wave & 1;
  const int rl = lane & 15, rg = lane >> 4;

  const int nbn = N >> 7;
  const int nwg = gridDim.x;                  // launched as multiple of 8
  const int bid = blockIdx.x;
  const int cpx = nwg >> 3;
  const int swz = (bid & 7) * cpx + (bid >> 3);
  const int bm = swz / nbn, bn = swz % nbn;

  const unsigned short* Ab = A + (size_t)bm * 128 * K;
  const unsigned short* Bb = Bt + (size_t)bn * 128 * K;

  f32x4 acc[4][4];
#pragma unroll
  for (int m = 0; m < 4; m++)
#pragma unroll
    for (int n = 0; n < 4; n++) acc[m][n] = (f32x4){0.f, 0.f, 0.f, 0.f};

  for (int kt = 0; kt < K; kt += 32) {
    if (kt) __syncthreads();
#pragma unroll
    for (int it = 0; it < 2; ++it) {
      int idx = it * 256 + t;
      int row = idx >> 2;
      int slot = idx & 3;
      int sl2 = slot ^ ((row >> 1) & 3);      // pre-swizzled global source
      unsigned short* ldsA = As + (size_t)(it * 256 + wave * 64) * 8; // wave-uniform
      unsigned short* ldsB = Bs + (size_t)(it * 256 + wave * 64) * 8;
      glds16(Ab + (size_t)row * K + kt + sl2 * 8, ldsA);
      glds16(Bb + (size_t)row * K + kt + sl2 * 8, ldsB);
    }
    __syncthreads();                          // drains vmcnt for gload_lds

    bf16x8 a[4], b[4];
#pragma unroll
    for (int m = 0; m < 4; m++) {
      int row = wr * 64 + m * 16 + rl;
      int sl2 = rg ^ ((row >> 1) & 3);        // swizzled read
      a[m] = *(const bf16x8*)&As[row * 32 + sl2 * 8];
    }
#pragma unroll
    for (int n = 0; n < 4; n++) {
      int row = wc * 64 + n * 16 + rl;
      int sl2 = rg ^ ((row >> 1) & 3);
      b[n] = *(const bf16x8*)&Bs[row * 32 + sl2 * 8];
    }
#pragma unroll
    for (int m = 0; m < 4; m++)
#pragma unroll
      for (int n = 0; n < 4; n++)
        acc[m][n] = mfma16(a[m], b[n], acc[m][n]);
  }

#pragma unroll
  for (int n = 0; n < 4; n++) {
    int col = bn * 128 + wc * 64 + n * 16 + rl;
    float bv = bias[col];
#pragma unroll
    for (int m = 0; m < 4; m++) {
      int row0 = bm * 128 + wr * 64 + m * 16 + rg * 4;
#pragma unroll
      for (int i = 0; i < 4; i++) {
        float v = acc[m][n][i] + bv;
        if (BF16_OUT)
          ((unsigned short*)Cout)[(size_t)(row0 + i) * N + col] = f2b(v);
        else
          ((float*)Cout)[(size_t)(row0 + i) * N + col] = v;
      }
    }
  }
}

// --------------------------- flash attention (split-K) ---------------------
// Persistent blocks (grid 1536 = 6/CU); units pulled off an atomic ticket
// counter, longest-first.  Unit = (head, 64-row q-strip, <=16 KV-tile chunk).
// 4 waves x 16 q-rows, single-buffered K/V (24KB LDS).
// Swapped QK^T, reg prefetch (T14), defer-max (T13), setprio (T5).
// Split units (qb>=16) write normalized partial O (bf16) + (m,l) f32.

__global__ __launch_bounds__(256) void attn_fwd(
    const unsigned short* __restrict__ qkv, unsigned short* __restrict__ aout,
    unsigned short* __restrict__ pscr, float* __restrict__ ml,
    unsigned int* __restrict__ qctr) {
  __shared__ unsigned short Kb[64 * 64];      // K rows   [key][hd]   (swz)
  __shared__ unsigned short Vb[64 * 64];      // V^T rows [hd][key]   (swz)
  __shared__ unsigned short Ps[4][16 * 64];   // per-wave P / V-row scratch (swz)
  __shared__ int sticket;

  const int tid = threadIdx.x;
  const int lane = tid & 63;
  const int w = tid >> 6;
  const int rl = lane & 15, rg = lane >> 4;

  unsigned short* Pw = Ps[w];
  const int skey = lane >> 3;                 // staging: key within group of 8
  const int slot = lane & 7;                  // staging: 8-elem hd slot

  for (;;) {
    if (tid == 0) sticket = (int)atomicAdd(qctr, 1u);
    __syncthreads();
    const int tk = sticket;
    if (tk >= NUM_UNITS) return;

    const int h = tk % ATT_H;
    const int u = 159 - (tk / ATT_H);         // long chunks first
    int qb, ck;
    if (u < 16)      { qb = u;                    ck = 0; }
    else if (u < 48) { qb = 16 + ((u - 16) >> 1); ck = (u - 16) & 1; }
    else if (u < 96) { qb = 32 + (u - 48) / 3;    ck = (u - 48) % 3; }
    else             { qb = 48 + ((u - 96) >> 2); ck = (u - 96) & 3; }

    const int nt = qb + 1;                    // total KV tiles for this strip
    const int t0 = ck * 16;
    const int t1 = min(nt, t0 + 16);
    const int qbase = qb * 64 + w * 16;

    // Q fragments, in registers for this unit
    bf16x8 qf[2];
#pragma unroll
    for (int ks = 0; ks < 2; ks++)
      qf[ks] = *(const bf16x8*)&qkv[(size_t)(qbase + rl) * ATT_3D + h * 64 + ks * 32 + rg * 8];

    float mS = -3.0e38f, lS = 0.f;
    f32x4 oacc[4];
#pragma unroll
    for (int hf = 0; hf < 4; hf++) oacc[hf] = (f32x4){0.f, 0.f, 0.f, 0.f};

    u16x8_t kr[2], vr[2];
    const size_t gstep = (size_t)64 * ATT_3D;
    const size_t gbase = (size_t)(w * 8 + skey) * ATT_3D + 768 + h * 64 + slot * 8;

    // prologue: stage tile t0 (K loads first, then V)
    {
      const size_t gb = gbase + (size_t)t0 * gstep;
      kr[0] = *(const u16x8_t*)&qkv[gb];
      kr[1] = *(const u16x8_t*)&qkv[gb + 32 * ATT_3D];
      vr[0] = *(const u16x8_t*)&qkv[gb + 768];
      vr[1] = *(const u16x8_t*)&qkv[gb + 32 * ATT_3D + 768];
#pragma unroll
      for (int it = 0; it < 2; ++it) {
        int key = it * 32 + w * 8 + skey;
        *(u16x8_t*)&Kb[swz8(key, slot)] = kr[it];
        *(u16x8_t*)&Pw[swz8(it * 8 + skey, slot)] = vr[it];
      }
#pragma unroll
      for (int kk = 0; kk < 2; ++kk) {
        u16x8_t g;
#pragma unroll
        for (int j = 0; j < 8; j++)
          g[j] = Pw[swz8(kk * 8 + j, lane >> 3) + (lane & 7)];
        *(u16x8_t*)&Vb[swz8(lane, kk * 4 + w)] = g;
      }
    }
    lbar();

    for (int t = t0; t < t1; ++t) {
      const bool pref = (t + 1 < t1);
      if (pref) {                             // K loads first, V after
        const size_t gb = gbase + (size_t)(t + 1) * gstep;
        kr[0] = *(const u16x8_t*)&qkv[gb];
        kr[1] = *(const u16x8_t*)&qkv[gb + 32 * ATT_3D];
        vr[0] = *(const u16x8_t*)&qkv[gb + 768];
        vr[1] = *(const u16x8_t*)&qkv[gb + 32 * ATT_3D + 768];
      }

      // ---- S^T = K @ Q^T ----
      f32x4 st[4];
#pragma unroll
      for (int kf = 0; kf < 4; kf++) st[kf] = (f32x4){0.f, 0.f, 0.f, 0.f};
      __builtin_amdgcn_s_setprio(1);
#pragma unroll
      for (int ks = 0; ks < 2; ks++) {
#pragma unroll
        for (int kf = 0; kf < 4; kf++) {
          bf16x8 kfr = *(const bf16x8*)&Kb[swz8(kf * 16 + rl, ks * 4 + rg)];
          st[kf] = mfma16(kfr, qf[ks], st[kf]);
        }
      }
      __builtin_amdgcn_s_setprio(0);

      lbar();                                 // A: QK reads of Kb done
      if (pref) {                             // K write (waits kr only)
#pragma unroll
        for (int it = 0; it < 2; ++it)
          *(u16x8_t*)&Kb[swz8(it * 32 + w * 8 + skey, slot)] = kr[it];
      }

      if (t == nt - 1) {                      // causal mask (only last tile)
#pragma unroll
        for (int kf = 0; kf < 4; kf++)
#pragma unroll
          for (int i = 0; i < 4; i++) {
            int key = t * 64 + kf * 16 + rg * 4 + i;
            if (key > qbase + rl) st[kf][i] = -3.0e38f;
          }
      }

      // ---- online softmax (key axis lane-local + 2 shuffles) ----
      float pm = fmaxf(fmaxf(st[0][0], st[0][1]), fmaxf(st[0][2], st[0][3]));
#pragma unroll
      for (int kf = 1; kf < 4; kf++)
        pm = fmaxf(pm, fmaxf(fmaxf(st[kf][0], st[kf][1]),
                             fmaxf(st[kf][2], st[kf][3])));
      pm = fmaxf(pm, __shfl_xor(pm, 16, 64));
      pm = fmaxf(pm, __shfl_xor(pm, 32, 64));
      if (!__all(pm - mS <= 8.f)) {           // defer-max: rescale rarely
        float mn = fmaxf(mS, pm);
        float fac = __expf(mS - mn);
        mS = mn;
        lS *= fac;
#pragma unroll
        for (int i = 0; i < 4; i++) {
          float fi = __shfl(fac, rg * 4 + i, 64);
#pragma unroll
          for (int hf = 0; hf < 4; hf++) oacc[hf][i] *= fi;
        }
      }
      const float mC = mS * LOG2E;            // exp(s-m) = exp2(s*log2e - mC)
      float psum = 0.f;
#pragma unroll
      for (int kf = 0; kf < 4; kf++) {
        float p0 = __builtin_amdgcn_exp2f(fmaf(st[kf][0], LOG2E, -mC));
        float p1 = __builtin_amdgcn_exp2f(fmaf(st[kf][1], LOG2E, -mC));
        float p2 = __builtin_amdgcn_exp2f(fmaf(st[kf][2], LOG2E, -mC));
        float p3 = __builtin_amdgcn_exp2f(fmaf(st[kf][3], LOG2E, -mC));
        psum += (p0 + p1) + (p2 + p3);
        uint2 d;                              // 2x v_cvt_pk_bf16_f32
        d.x = cvtpk(p0, p1);
        d.y = cvtpk(p2, p3);
        // store via short-family vector (TBAA-safe vs Pw reads)
        *(u16x4_t*)&Pw[swz8(rl, kf * 2 + (rg >> 1)) + (rg & 1) * 4] =
            __builtin_bit_cast(u16x4_t, d);
      }
      psum += __shfl_xor(psum, 16, 64);
      psum += __shfl_xor(psum, 32, 64);
      lS += psum;

      // ---- PV : O += P @ V ----
      __builtin_amdgcn_s_setprio(1);
#pragma unroll
      for (int ks2 = 0; ks2 < 2; ks2++) {
        bf16x8 pa = *(const bf16x8*)&Pw[swz8(rl, ks2 * 4 + rg)];
#pragma unroll
        for (int hf = 0; hf < 4; hf++) {
          bf16x8 vbf = *(const bf16x8*)&Vb[swz8(hf * 16 + rl, ks2 * 4 + rg)];
          oacc[hf] = mfma16(pa, vbf, oacc[hf]);
        }
      }
      __builtin_amdgcn_s_setprio(0);

      lbar();                                 // B: PV reads of Vb done
      if (pref) {                             // V write + in-LDS transpose
#pragma unroll
        for (int it = 0; it < 2; ++it)
          *(u16x8_t*)&Pw[swz8(it * 8 + skey, slot)] = vr[it];
#pragma unroll
        for (int kk = 0; kk < 2; ++kk) {
          u16x8_t g;
#pragma unroll
          for (int j = 0; j < 8; j++)
            g[j] = Pw[swz8(kk * 8 + j, lane >> 3) + (lane & 7)];
          *(u16x8_t*)&Vb[swz8(lane, kk * 4 + w)] = g;
        }
      }
    }

    // ---- epilogue: write normalized O (final or partial) ----
    const bool split = (qb >= 16);
    unsigned short* dst;
    int pitch;
    if (!split || ck == 0) {
      dst = aout + (size_t)(qb * 64) * ATT_D + h * 64;
      pitch = ATT_D;
    } else {
      int s;
      if (qb < 32)      s = h * 96 + (qb - 16);
      else if (qb < 48) s = h * 96 + 16 + (qb - 32) * 2 + (ck - 1);
      else              s = h * 96 + 48 + (qb - 48) * 3 + (ck - 1);
      dst = pscr + (size_t)s * 4096;
      pitch = 64;
    }
    if (split && rg == 0) {                   // (m,l) per q-row, once
      int unit = h * 48 + (qb - 16);
      float2* mlp = (float2*)ml;
      mlp[(unit * 4 + ck) * 64 + w * 16 + rl] = make_float2(mS, lS);
    }
#pragma unroll
    for (int i = 0; i < 4; i++) {
      float li = __shfl(lS, rg * 4 + i, 64);
      float inv = 1.f / li;
      int qrow = w * 16 + rg * 4 + i;
#pragma unroll
      for (int hf = 0; hf < 4; hf++)
        dst[(size_t)qrow * pitch + hf * 16 + rl] = f2b(oacc[hf][i] * inv);
    }
    __syncthreads();                          // all LDS reads done before next unit
  }
}

// --------------------------- split-K combine -------------------------------
// One block per split unit (h, qb>=16).  256 thr: thread = (q, 16-col part).

__global__ __launch_bounds__(256) void attn_combine(
    const unsigned short* __restrict__ pscr, const float* __restrict__ ml,
    unsigned short* __restrict__ ao) {
  const int unit = blockIdx.x;                // 576 = 12 * 48
  const int h = unit / 48, uqb = unit % 48, qb = uqb + 16;
  const int nch = (qb + 16) >> 4;             // ceil((qb+1)/16), 2..4
  const int tid = threadIdx.x;
  const int q = tid >> 2, part = tid & 3;

  const float2* mlp = (const float2*)ml;
  float m[4], l[4];
  float M = -3.0e38f;
  for (int c = 0; c < nch; ++c) {
    float2 p = mlp[(unit * 4 + c) * 64 + q];
    m[c] = p.x; l[c] = p.y;
    M = fmaxf(M, m[c]);
  }
  float wgt[4], den = 0.f;
  for (int c = 0; c < nch; ++c) {
    wgt[c] = l[c] * __expf(m[c] - M);
    den += wgt[c];
  }

  float acc[16];
#pragma unroll
  for (int j = 0; j < 16; j++) acc[j] = 0.f;

  unsigned short* aorow = ao + (size_t)(qb * 64 + q) * ATT_D + h * 64 + part * 16;
  for (int c = 0; c < nch; ++c) {
    const unsigned short* src;
    if (c == 0) {
      src = aorow;
    } else {
      int s;
      if (qb < 32)      s = h * 96 + (qb - 16);
      else if (qb < 48) s = h * 96 + 16 + (qb - 32) * 2 + (c - 1);
      else              s = h * 96 + 48 + (qb - 48) * 3 + (c - 1);
      src = pscr + (size_t)s * 4096 + q * 64 + part * 16;
    }
    u16x8_t v0 = *(const u16x8_t*)src;
    u16x8_t v1 = *(const u16x8_t*)(src + 8);
#pragma unroll
    for (int j = 0; j < 8; j++) acc[j] += wgt[c] * b2f(v0[j]);
#pragma unroll
    for (int j = 0; j < 8; j++) acc[8 + j] += wgt[c] * b2f(v1[j]);
  }
  float inv = 1.f / den;
  u16x8_t o0, o1;
#pragma unroll
  for (int j = 0; j < 8; j++) { o0[j] = f2b(acc[j] * inv); o1[j] = f2b(acc[8 + j] * inv); }
  *(u16x8_t*)aorow = o0;
  *(u16x8_t*)(aorow + 8) = o1;
}

// ------------------------------- launcher ----------------------------------

extern "C" void kernel_launch(void* const* d_in, const int* in_sizes, int n_in,
                              void* d_out, int out_size, void* d_ws, size_t ws_size,
                              hipStream_t stream) {
  const float* x      = (const float*)d_in[0];
  const float* W_attn = (const float*)d_in[1];
  const float* b_attn = (const float*)d_in[2];
  const float* W_proj = (const float*)d_in[3];
  const float* b_proj = (const float*)d_in[4];
  float* out = (float*)d_out;

  char* ws = (char*)d_ws;
  unsigned short* xb  = (unsigned short*)(ws);              //  6,291,456 B
  unsigned short* WaT = (unsigned short*)(ws + 6291456);    //  3,538,944 B
  unsigned short* WpT = (unsigned short*)(ws + 9830400);    //  1,179,648 B
  unsigned short* qkv = (unsigned short*)(ws + 11010048);   // 18,874,368 B
  unsigned short* ao  = (unsigned short*)(ws + 29884416);   //  6,291,456 B
  // split-K scratch (aliases regions that are dead during attention):
  unsigned short* pscr = (unsigned short*)(ws);             // 9,437,184 B (xb+WaT)
  unsigned int*   qctr = (unsigned int*)(ws + 9437184);     // ticket counter (WaT tail slack)
  float*          ml   = (float*)(ws + 9830400);            // 1,179,648 B (WpT)

  convert_f32_bf16<<<3072, 256, 0, stream>>>(x, xb, 786432);           // 4096*768/4
  transpose_conv<<<dim3(72, 24), 256, 0, stream>>>(W_attn, WaT, 768, 2304);

  gemm_bias<1><<<576, 256, 0, stream>>>(xb, WaT, b_attn, qkv, 4096, 2304, 768);
  hipMemsetAsync(qctr, 0, 4, stream);         // after gemm1 (WaT tail now dead)
  attn_fwd<<<1536, 256, 0, stream>>>(qkv, ao, pscr, ml, qctr);
  attn_combine<<<576, 256, 0, stream>>>(pscr, ml, ao);

  // WpT region doubled as ml during attention; transpose W_proj only now.
  transpose_conv<<<dim3(24, 24), 256, 0, stream>>>(W_proj, WpT, 768, 768);
  gemm_bias<0><<<192, 256, 0, stream>>>(ao, WpT, b_proj, out, 4096, 768, 768);
}

// Round 9
// 128.193 us; speedup vs baseline: 1.1631x; 1.1631x over previous
//
#include <hip/hip_runtime.h>

// ---------------------------------------------------------------------------
// GPT-2 style MHA block: qkv = x@W_attn+b; causal softmax(QK^T)V; out@W_proj+b
// B=1, S=4096, D=768, H=12, HD=64.  All heavy math in bf16 MFMA (fp32 accum).
// Attention: split-K flash decoding with 32x32x16 MFMA, 4 waves x 32 q-rows,
// P fully in registers (cvt_pk + shfl_xor(32) exchange), single-buffered K/V
// LDS (24KB), two raw barriers per tile (lgkmcnt-only).  Fixed unit mapping
// (round-8 queue destroyed L2 locality: FETCH 17->99MB).
// ---------------------------------------------------------------------------

typedef short bf16x8 __attribute__((ext_vector_type(8)));      // MFMA A/B frag
typedef float f32x16 __attribute__((ext_vector_type(16)));     // 32x32 C/D frag
typedef unsigned short u16x8_t __attribute__((ext_vector_type(8)));
typedef unsigned short u16x4_t __attribute__((ext_vector_type(4)));
typedef unsigned int   u32x4_t __attribute__((ext_vector_type(4)));
typedef float f32x4 __attribute__((ext_vector_type(4)));       // 16x16 C/D (gemm)

#define ATT_S  4096
#define ATT_D  768
#define ATT_3D 2304
#define ATT_H  12
#define LOG2E  1.44269504089f

__device__ __forceinline__ unsigned short f2b(float f) {
  union { float f; unsigned int u; } v; v.f = f;
  unsigned int r = v.u + 0x7fffu + ((v.u >> 16) & 1u);   // RNE
  return (unsigned short)(r >> 16);
}
__device__ __forceinline__ float b2f(unsigned short b) {
  union { unsigned int u; float f; } v; v.u = ((unsigned int)b) << 16;
  return v.f;
}
__device__ __forceinline__ unsigned int cvtpk(float a, float b) {
  unsigned int r;
  asm("v_cvt_pk_bf16_f32 %0, %1, %2" : "=v"(r) : "v"(a), "v"(b));
  return r;
}

__device__ __forceinline__ f32x4 mfma16(bf16x8 a, bf16x8 b, f32x4 c) {
  return __builtin_amdgcn_mfma_f32_16x16x32_bf16(a, b, c, 0, 0, 0);
}
__device__ __forceinline__ f32x16 mfma32(bf16x8 a, bf16x8 b, f32x16 c) {
  return __builtin_amdgcn_mfma_f32_32x32x16_bf16(a, b, c, 0, 0, 0);
}

__device__ __forceinline__ void glds16(const void* g, void* l) {
  __builtin_amdgcn_global_load_lds((__attribute__((address_space(1))) void*)g,
                                   (__attribute__((address_space(3))) void*)l,
                                   16, 0, 0);
}

// raw barrier: LDS ops complete, NO vmcnt drain (prefetch stays in flight).
__device__ __forceinline__ void lbar() {
  asm volatile("s_waitcnt lgkmcnt(0)" ::: "memory");
  __builtin_amdgcn_s_barrier();
}

// 16B chunk c of row `row` in a pitch-64 bf16 LDS tile, XOR slot swizzle (T2).
__device__ __forceinline__ int swz8(int row, int c) {
  return row * 64 + ((c ^ (row & 7)) << 3);
}

// --------------------------- pre-pass kernels ------------------------------

__global__ __launch_bounds__(256) void convert_f32_bf16(
    const float* __restrict__ in, unsigned short* __restrict__ out, int n4) {
  int i = blockIdx.x * 256 + threadIdx.x;
  if (i >= n4) return;
  float4 v = ((const float4*)in)[i];
  u16x4_t o;
  o[0] = f2b(v.x); o[1] = f2b(v.y); o[2] = f2b(v.z); o[3] = f2b(v.w);
  ((u16x4_t*)out)[i] = o;
}

__global__ __launch_bounds__(256) void transpose_conv(
    const float* __restrict__ W, unsigned short* __restrict__ WT, int K, int N) {
  __shared__ float tile[32][33];
  int bx = blockIdx.x, by = blockIdx.y;
  int tx = threadIdx.x & 31, ty = threadIdx.x >> 5;
#pragma unroll
  for (int k = 0; k < 4; k++)
    tile[ty + k * 8][tx] = W[(size_t)(by * 32 + ty + k * 8) * N + bx * 32 + tx];
  __syncthreads();
#pragma unroll
  for (int k = 0; k < 4; k++)
    WT[(size_t)(bx * 32 + ty + k * 8) * K + by * 32 + tx] = f2b(tile[tx][ty + k * 8]);
}

// --------------------------- bf16 MFMA GEMM --------------------------------

template <int BF16_OUT>
__global__ __launch_bounds__(256) void gemm_bias(
    const unsigned short* __restrict__ A, const unsigned short* __restrict__ Bt,
    const float* __restrict__ bias, void* __restrict__ Cout,
    int M, int N, int K) {
  __shared__ unsigned short As[128 * 32];
  __shared__ unsigned short Bs[128 * 32];
  const int t = threadIdx.x;
  const int lane = t & 63;
  const int wave = t >> 6;
  const int wr = wave >> 1, wc = wave & 1;
  const int rl = lane & 15, rg = lane >> 4;

  const int nbn = N >> 7;
  const int nwg = gridDim.x;
  const int bid = blockIdx.x;
  const int cpx = nwg >> 3;
  const int swz = (bid & 7) * cpx + (bid >> 3);
  const int bm = swz / nbn, bn = swz % nbn;

  const unsigned short* Ab = A + (size_t)bm * 128 * K;
  const unsigned short* Bb = Bt + (size_t)bn * 128 * K;

  f32x4 acc[4][4];
#pragma unroll
  for (int m = 0; m < 4; m++)
#pragma unroll
    for (int n = 0; n < 4; n++) acc[m][n] = (f32x4){0.f, 0.f, 0.f, 0.f};

  for (int kt = 0; kt < K; kt += 32) {
    if (kt) __syncthreads();
#pragma unroll
    for (int it = 0; it < 2; ++it) {
      int idx = it * 256 + t;
      int row = idx >> 2;
      int slot = idx & 3;
      int sl2 = slot ^ ((row >> 1) & 3);
      unsigned short* ldsA = As + (size_t)(it * 256 + wave * 64) * 8;
      unsigned short* ldsB = Bs + (size_t)(it * 256 + wave * 64) * 8;
      glds16(Ab + (size_t)row * K + kt + sl2 * 8, ldsA);
      glds16(Bb + (size_t)row * K + kt + sl2 * 8, ldsB);
    }
    __syncthreads();

    bf16x8 a[4], b[4];
#pragma unroll
    for (int m = 0; m < 4; m++) {
      int row = wr * 64 + m * 16 + rl;
      int sl2 = rg ^ ((row >> 1) & 3);
      a[m] = *(const bf16x8*)&As[row * 32 + sl2 * 8];
    }
#pragma unroll
    for (int n = 0; n < 4; n++) {
      int row = wc * 64 + n * 16 + rl;
      int sl2 = rg ^ ((row >> 1) & 3);
      b[n] = *(const bf16x8*)&Bs[row * 32 + sl2 * 8];
    }
#pragma unroll
    for (int m = 0; m < 4; m++)
#pragma unroll
      for (int n = 0; n < 4; n++)
        acc[m][n] = mfma16(a[m], b[n], acc[m][n]);
  }

#pragma unroll
  for (int n = 0; n < 4; n++) {
    int col = bn * 128 + wc * 64 + n * 16 + rl;
    float bv = bias[col];
#pragma unroll
    for (int m = 0; m < 4; m++) {
      int row0 = bm * 128 + wr * 64 + m * 16 + rg * 4;
#pragma unroll
      for (int i = 0; i < 4; i++) {
        float v = acc[m][n][i] + bv;
        if (BF16_OUT)
          ((unsigned short*)Cout)[(size_t)(row0 + i) * N + col] = f2b(v);
        else
          ((float*)Cout)[(size_t)(row0 + i) * N + col] = v;
      }
    }
  }
}

// --------------------------- flash attention (split-K, 32x32) --------------
// Unit = (head, 128-row q-strip, chunk of <=16 KV tiles of 64 keys).
// 960 units = 12 x 80; fixed longest-first mapping.  4 waves x 32 q-rows.
// Swapped QK^T 32x32: lane holds S[16 keys][q=lane&31]; lane^32 has the
// complementary key half -> softmax reduce = 31 fmax + 1 shfl.  P assembled
// in-register (cvt_pk + shfl_xor(32)); O^T accumulated (col=lane&31=q) so
// rescale/row-sum/epilogue are per-lane scalar.  K/V^T single-buffered LDS,
// two lgkmcnt-only barriers per tile, reg prefetch (T14), defer-max (T13),
// setprio (T5).

__global__ __launch_bounds__(256) void attn_fwd(
    const unsigned short* __restrict__ qkv, unsigned short* __restrict__ aout,
    unsigned short* __restrict__ pscr, float* __restrict__ ml) {
  __shared__ unsigned short Kb[64 * 64];      // K rows  [key][hd]  (swz)
  __shared__ unsigned short Vt[64 * 64];      // V^T     [hd][key]  (swz)
  __shared__ unsigned short Vrow[64 * 64];    // V rows staging     (swz)

  const int tid = threadIdx.x;
  const int lane = tid & 63;
  const int w = tid >> 6;
  const int l31 = lane & 31, h5 = lane >> 5;

  const int bid = blockIdx.x;
  const int h = bid % ATT_H;
  const int u = 79 - (bid / ATT_H);           // long chunks dispatched first
  int sb, ck;
  if (u < 8)       { sb = u;                    ck = 0; }
  else if (u < 24) { sb = 8 + ((u - 8) >> 1);   ck = (u - 8) & 1; }
  else if (u < 48) { sb = 16 + (u - 24) / 3;    ck = (u - 24) % 3; }
  else             { sb = 24 + ((u - 48) >> 2); ck = (u - 48) & 3; }

  const int nt = 2 * sb + 2;                  // KV tiles for this strip
  const int t0 = ck * 16;
  const int t1 = min(nt, t0 + 16);
  const int q = sb * 128 + w * 32 + l31;      // this lane's q row

  const int skey = tid >> 3;                  // staging: key (0..31) + 32*pass
  const int slot = tid & 7;                   // staging: 8-elem hd slot

  // Q fragments (full 64-hd row per lane, 4 frags of k=16)
  bf16x8 qf[4];
#pragma unroll
  for (int ks = 0; ks < 4; ks++)
    qf[ks] = *(const bf16x8*)&qkv[(size_t)q * ATT_3D + h * 64 + ks * 16 + h5 * 8];

  float mS = -3.0e38f, lS = 0.f;
  f32x16 oa0 = (f32x16)(0.f), oa1 = (f32x16)(0.f);   // O^T hd-groups 0/1

  u16x8_t kr[2], vr[2];
  const size_t gstep = (size_t)64 * ATT_3D;
  const size_t gbase = (size_t)skey * ATT_3D + 768 + h * 64 + slot * 8;

  // prologue: stage tile t0 (K rows + V rows), build V^T
  {
    const size_t gb = gbase + (size_t)t0 * gstep;
    kr[0] = *(const u16x8_t*)&qkv[gb];
    kr[1] = *(const u16x8_t*)&qkv[gb + 32 * ATT_3D];
    vr[0] = *(const u16x8_t*)&qkv[gb + 768];
    vr[1] = *(const u16x8_t*)&qkv[gb + 32 * ATT_3D + 768];
#pragma unroll
    for (int p = 0; p < 2; ++p) {
      *(u16x8_t*)&Kb[swz8(p * 32 + skey, slot)] = kr[p];
      *(u16x8_t*)&Vrow[swz8(p * 32 + skey, slot)] = vr[p];
    }
#pragma unroll
    for (int kk = 0; kk < 2; ++kk) {          // within-wave transpose
      int kb = w + kk * 4;
      u16x8_t g;
#pragma unroll
      for (int j = 0; j < 8; j++)
        g[j] = Vrow[swz8(kb * 8 + j, lane >> 3) + (lane & 7)];
      *(u16x8_t*)&Vt[swz8(lane, kb)] = g;
    }
  }
  lbar();

  for (int t = t0; t < t1; ++t) {
    const bool pref = (t + 1 < t1);
    const bool active = (t * 64 <= sb * 128 + w * 32 + 31);
    if (pref) {                               // issue next-tile loads early
      const size_t gb = gbase + (size_t)(t + 1) * gstep;
      kr[0] = *(const u16x8_t*)&qkv[gb];
      kr[1] = *(const u16x8_t*)&qkv[gb + 32 * ATT_3D];
      vr[0] = *(const u16x8_t*)&qkv[gb + 768];
      vr[1] = *(const u16x8_t*)&qkv[gb + 32 * ATT_3D + 768];
    }

    f32x16 st[2];
    st[0] = (f32x16)(0.f); st[1] = (f32x16)(0.f);
    if (active) {                             // ---- S^T = K @ Q^T ----
      __builtin_amdgcn_s_setprio(1);
#pragma unroll
      for (int kg = 0; kg < 2; kg++)
#pragma unroll
        for (int ks = 0; ks < 4; ks++) {
          bf16x8 kfr = *(const bf16x8*)&Kb[swz8(kg * 32 + l31, ks * 2 + h5)];
          st[kg] = mfma32(kfr, qf[ks], st[kg]);
        }
      __builtin_amdgcn_s_setprio(0);
    }

    lbar();                                   // A: QK reads of Kb done
    if (pref) {                               // K write (waits kr only)
#pragma unroll
      for (int p = 0; p < 2; ++p)
        *(u16x8_t*)&Kb[swz8(p * 32 + skey, slot)] = kr[p];
    }

    if (active) {
      if (t * 64 + 63 > sb * 128 + w * 32) {  // causal mask
#pragma unroll
        for (int kg = 0; kg < 2; kg++)
#pragma unroll
          for (int r = 0; r < 16; r++) {
            int key = t * 64 + kg * 32 + (r & 3) + 8 * (r >> 2) + 4 * h5;
            if (key > q) st[kg][r] = -3.0e38f;
          }
      }

      // ---- online softmax: per-lane 32 vals + 1 cross-half shuffle ----
      float pm = st[0][0];
#pragma unroll
      for (int r = 1; r < 16; r++) pm = fmaxf(pm, st[0][r]);
#pragma unroll
      for (int r = 0; r < 16; r++) pm = fmaxf(pm, st[1][r]);
      pm = fmaxf(pm, __shfl_xor(pm, 32, 64));
      if (!__all(pm - mS <= 8.f)) {           // defer-max: rescale rarely
        float mn = fmaxf(mS, pm);
        float fac = __expf(mS - mn);
        mS = mn;
        lS *= fac;
#pragma unroll
        for (int r = 0; r < 16; r++) { oa0[r] *= fac; oa1[r] *= fac; }
      }
      const float mC = mS * LOG2E;
      float psum = 0.f;
#pragma unroll
      for (int kg = 0; kg < 2; kg++)
#pragma unroll
        for (int r = 0; r < 16; r++) {
          float p = __builtin_amdgcn_exp2f(fmaf(st[kg][r], LOG2E, -mC));
          st[kg][r] = p;
          psum += p;
        }
      psum += __shfl_xor(psum, 32, 64);
      lS += psum;

      // ---- P assembly (registers only) + PV ----
      __builtin_amdgcn_s_setprio(1);
#pragma unroll
      for (int kc = 0; kc < 4; kc++) {
        const int kg = kc >> 1;
        const int rb = (kc & 1) << 3;
        unsigned e00 = cvtpk(st[kg][rb + 0], st[kg][rb + 1]);  // octet 2kc
        unsigned e01 = cvtpk(st[kg][rb + 2], st[kg][rb + 3]);
        unsigned e10 = cvtpk(st[kg][rb + 4], st[kg][rb + 5]);  // octet 2kc+1
        unsigned e11 = cvtpk(st[kg][rb + 6], st[kg][rb + 7]);
        unsigned own0 = h5 ? e10 : e00, own1 = h5 ? e11 : e01;
        unsigned snd0 = h5 ? e00 : e10, snd1 = h5 ? e01 : e11;
        unsigned r0 = (unsigned)__shfl_xor((int)snd0, 32, 64);
        unsigned r1 = (unsigned)__shfl_xor((int)snd1, 32, 64);
        u32x4_t fd;
        fd[0] = h5 ? r0 : own0; fd[1] = h5 ? r1 : own1;
        fd[2] = h5 ? own0 : r0; fd[3] = h5 ? own1 : r1;
        bf16x8 pfr = __builtin_bit_cast(bf16x8, fd);
        bf16x8 v0 = *(const bf16x8*)&Vt[swz8(l31, kc * 2 + h5)];
        bf16x8 v1 = *(const bf16x8*)&Vt[swz8(32 + l31, kc * 2 + h5)];
        oa0 = mfma32(v0, pfr, oa0);
        oa1 = mfma32(v1, pfr, oa1);
      }
      __builtin_amdgcn_s_setprio(0);
    }

    lbar();                                   // B: PV reads of Vt done
    if (pref) {                               // V rows + within-wave transpose
#pragma unroll
      for (int p = 0; p < 2; ++p)
        *(u16x8_t*)&Vrow[swz8(p * 32 + skey, slot)] = vr[p];
#pragma unroll
      for (int kk = 0; kk < 2; ++kk) {
        int kb = w + kk * 4;
        u16x8_t g;
#pragma unroll
        for (int j = 0; j < 8; j++)
          g[j] = Vrow[swz8(kb * 8 + j, lane >> 3) + (lane & 7)];
        *(u16x8_t*)&Vt[swz8(lane, kb)] = g;
      }
    }
  }

  // ---- epilogue: write normalized O (final or partial) ----
  const bool split = (sb >= 8);
  unsigned short* dst;
  int pitch;
  if (!split || ck == 0) {
    dst = aout + (size_t)q * ATT_D + h * 64;
    pitch = 0;                                // row already applied
  } else {
    int sbase = (sb < 16) ? (sb - 8)
              : (sb < 24) ? 8 + (sb - 16) * 2
                          : 24 + (sb - 24) * 3;
    int s = h * 48 + sbase + (ck - 1);
    dst = pscr + (size_t)s * 8192 + (w * 32 + l31) * 64;
    pitch = 0;
  }
  if (split && lane < 32) {                   // (m,l) per q-row, once
    int b2 = (sb < 16) ? (sb - 8) * 2
           : (sb < 24) ? 16 + (sb - 16) * 3
                       : 40 + (sb - 24) * 4;
    float2* mlp = (float2*)ml;
    mlp[(size_t)(h * 72 + b2 + ck) * 128 + w * 32 + lane] = make_float2(mS, lS);
  }
  const float inv = 1.f / lS;
#pragma unroll
  for (int hg = 0; hg < 2; hg++)
#pragma unroll
    for (int rq = 0; rq < 4; rq++) {
      u16x4_t o4;
#pragma unroll
      for (int c = 0; c < 4; c++) {
        float v = (hg ? oa1[rq * 4 + c] : oa0[rq * 4 + c]) * inv;
        o4[c] = f2b(v);
      }
      *(u16x4_t*)&dst[hg * 32 + rq * 8 + h5 * 4] = o4;
    }
}

// --------------------------- split-K combine -------------------------------
// One block per split strip (h, sb>=8): 288 = 12 x 24.  256 thr: (q, colhalf).

__global__ __launch_bounds__(256) void attn_combine(
    const unsigned short* __restrict__ pscr, const float* __restrict__ ml,
    unsigned short* __restrict__ ao) {
  const int unit = blockIdx.x;
  const int h = unit / 24, sb = unit % 24 + 8;
  const int nch = (sb < 16) ? 2 : (sb < 24) ? 3 : 4;
  const int tid = threadIdx.x;
  const int qr = tid >> 1, part = tid & 1;    // q-row 0..127, col half 0..1

  const int b2 = (sb < 16) ? (sb - 8) * 2
               : (sb < 24) ? 16 + (sb - 16) * 3
                           : 40 + (sb - 24) * 4;
  const int sbase = (sb < 16) ? (sb - 8)
                  : (sb < 24) ? 8 + (sb - 16) * 2
                              : 24 + (sb - 24) * 3;

  const float2* mlp = (const float2*)ml;
  float m[4], l[4];
  float M = -3.0e38f;
  for (int c = 0; c < nch; ++c) {
    float2 p = mlp[(size_t)(h * 72 + b2 + c) * 128 + qr];
    m[c] = p.x; l[c] = p.y;
    M = fmaxf(M, m[c]);
  }
  float wgt[4], den = 0.f;
  for (int c = 0; c < nch; ++c) {
    wgt[c] = l[c] * __expf(m[c] - M);
    den += wgt[c];
  }

  float acc[32];
#pragma unroll
  for (int j = 0; j < 32; j++) acc[j] = 0.f;

  unsigned short* aorow =
      ao + (size_t)(sb * 128 + qr) * ATT_D + h * 64 + part * 32;
  for (int c = 0; c < nch; ++c) {
    const unsigned short* src =
        (c == 0) ? aorow
                 : pscr + (size_t)(h * 48 + sbase + (c - 1)) * 8192 +
                       qr * 64 + part * 32;
#pragma unroll
    for (int v = 0; v < 4; v++) {
      u16x8_t x = *(const u16x8_t*)(src + v * 8);
#pragma unroll
      for (int j = 0; j < 8; j++) acc[v * 8 + j] += wgt[c] * b2f(x[j]);
    }
  }
  float invd = 1.f / den;
#pragma unroll
  for (int v = 0; v < 4; v++) {
    u16x8_t o;
#pragma unroll
    for (int j = 0; j < 8; j++) o[j] = f2b(acc[v * 8 + j] * invd);
    *(u16x8_t*)(aorow + v * 8) = o;
  }
}

// ------------------------------- launcher ----------------------------------

extern "C" void kernel_launch(void* const* d_in, const int* in_sizes, int n_in,
                              void* d_out, int out_size, void* d_ws, size_t ws_size,
                              hipStream_t stream) {
  const float* x      = (const float*)d_in[0];
  const float* W_attn = (const float*)d_in[1];
  const float* b_attn = (const float*)d_in[2];
  const float* W_proj = (const float*)d_in[3];
  const float* b_proj = (const float*)d_in[4];
  float* out = (float*)d_out;

  char* ws = (char*)d_ws;
  unsigned short* xb  = (unsigned short*)(ws);              //  6,291,456 B
  unsigned short* WaT = (unsigned short*)(ws + 6291456);    //  3,538,944 B
  unsigned short* WpT = (unsigned short*)(ws + 9830400);    //  1,179,648 B
  unsigned short* qkv = (unsigned short*)(ws + 11010048);   // 18,874,368 B
  unsigned short* ao  = (unsigned short*)(ws + 29884416);   //  6,291,456 B
  // split-K scratch (aliases regions dead during attention):
  unsigned short* pscr = (unsigned short*)(ws);             // 576*16KB = 9,437,184 B
  float*          ml   = (float*)(ws + 9830400);            // 884,736 B used (WpT)

  convert_f32_bf16<<<3072, 256, 0, stream>>>(x, xb, 786432);
  transpose_conv<<<dim3(72, 24), 256, 0, stream>>>(W_attn, WaT, 768, 2304);

  gemm_bias<1><<<576, 256, 0, stream>>>(xb, WaT, b_attn, qkv, 4096, 2304, 768);
  attn_fwd<<<960, 256, 0, stream>>>(qkv, ao, pscr, ml);
  attn_combine<<<288, 256, 0, stream>>>(pscr, ml, ao);

  // WpT region doubled as ml during attention; transpose W_proj only now.
  transpose_conv<<<dim3(24, 24), 256, 0, stream>>>(W_proj, WpT, 768, 768);
  gemm_bias<0><<<192, 256, 0, stream>>>(ao, WpT, b_proj, out, 4096, 768, 768);
}